// Round 1
// baseline (108.136 us; speedup 1.0000x reference)
//
#include <hip/hip_runtime.h>

typedef __attribute__((ext_vector_type(8))) short short8;
typedef __attribute__((ext_vector_type(4))) float floatx4;

#define LEAKY 0.2f
#define NEGM -9e15f

// --- bf16 helpers (RNE, finite inputs) ---
__device__ __forceinline__ unsigned short f2bf(float f) {
  unsigned int u = __float_as_uint(f);
  u = u + 0x7FFFu + ((u >> 16) & 1u);
  return (unsigned short)(u >> 16);
}
__device__ __forceinline__ float bf2f(short s) {
  return __uint_as_float(((unsigned int)(unsigned short)s) << 16);
}

// Stage one 16 KB tile (32 rows x 512 B) global->LDS, linear dest, width=16.
__device__ __forceinline__ void stage16k(const void* gsrc, void* ldst, int tid) {
  const int w = tid >> 6, l = tid & 63;
#pragma unroll
  for (int i = 0; i < 4; ++i) {
    const int off = i * 4096 + w * 1024;
    __builtin_amdgcn_global_load_lds(
        (const __attribute__((address_space(1))) unsigned int*)((const unsigned char*)gsrc + off + l * 16),
        (__attribute__((address_space(3))) unsigned int*)((unsigned char*)ldst + off),
        16, 0, 0);
  }
}

// ---------------------------------------------------------------------------
// Prep: h fp32 [64][256][256] -> Hsw (row-major bf16, per-row XOR swizzle baked)
//                             -> HTsw (transposed bf16, per-row XOR swizzle baked)
// swizzle: element d' = d ^ ((row&7)<<3)  (bits 4..6 of byte offset)
// ---------------------------------------------------------------------------
__global__ __launch_bounds__(256) void prep_kernel(
    const float* __restrict__ h, unsigned short* __restrict__ Hsw,
    unsigned short* __restrict__ HTsw) {
  const int b = blockIdx.x >> 2, q = blockIdx.x & 3;
  const int t = threadIdx.x;
  const float* hb = h + b * 65536;
  unsigned short* Hb = Hsw + b * 65536;
  unsigned short* HTb = HTsw + b * 65536;
  // Part A: Hsw rows m in [64q, 64q+64)
#pragma unroll
  for (int j = 0; j < 8; ++j) {
    int c = t + j * 256;              // 0..2047
    int m = 64 * q + (c >> 5);
    int d0 = (c & 31) * 8;
    const float4* src = (const float4*)(hb + m * 256 + d0);
    float4 x = src[0], y = src[1];
    short8 v;
    v[0] = (short)f2bf(x.x); v[1] = (short)f2bf(x.y);
    v[2] = (short)f2bf(x.z); v[3] = (short)f2bf(x.w);
    v[4] = (short)f2bf(y.x); v[5] = (short)f2bf(y.y);
    v[6] = (short)f2bf(y.z); v[7] = (short)f2bf(y.w);
    *(short8*)(Hb + m * 256 + (d0 ^ ((m & 7) << 3))) = v;
  }
  // Part B: HTsw rows d in [64q, 64q+64): HTsw[b][d][m'] = h[b][m][d]
#pragma unroll
  for (int j = 0; j < 8; ++j) {
    int p = t + j * 256;
    int d = 64 * q + (p & 63);
    int m0 = (p >> 6) * 8;            // (t>>6) + 4*j in 0..31, times 8
    short8 v;
#pragma unroll
    for (int jj = 0; jj < 8; ++jj) v[jj] = (short)f2bf(hb[(m0 + jj) * 256 + d]);
    *(short8*)(HTb + d * 256 + (m0 ^ ((d & 7) << 3))) = v;
  }
}

// ---------------------------------------------------------------------------
// Fused: per block = (b, 64 n-rows). 4 waves x 16 rows each.
// Phase 1: logits[64][256] via bf16 MFMA (A_k = h*a_k in regs), adj-select,
//          leaky, in-register softmax -> alpha bf16 in LDS (swizzled).
// Phase 2: out = alpha @ H via HTsw tiles; rsqrt-normalize + residual.
// LDS: [0,32K) Asw then alpha; [32K,48K)+[48K,64K) B double-buffer (a_lds
// aliases buf1 during setup only).
// ---------------------------------------------------------------------------
__global__ __launch_bounds__(256, 1) void fused_kernel(
    const float* __restrict__ h, const int* __restrict__ adj,
    const float* __restrict__ a, float* __restrict__ out,
    const unsigned short* __restrict__ Hsw, const unsigned short* __restrict__ HTsw) {
  __shared__ __align__(16) unsigned char lds[65536];
  unsigned short* ldsU = (unsigned short*)lds;
  const int tid = threadIdx.x;
  const int w = tid >> 6, l = tid & 63;
  const int l16 = l & 15, lhi = l >> 4;
  // XCD-bijective swizzle: 4 blocks of same b land on same XCD (256 = 8*32)
  const int id = blockIdx.x;
  const int b = (id & 7) + 8 * (id >> 5);
  const int nblk = (id >> 3) & 3;
  const int n0 = nblk * 64;

  const float* hb = h + b * 65536;
  const int* adjb = adj + b * 65536;
  const unsigned short* HswB = Hsw + b * 65536;
  const unsigned short* HTswB = HTsw + b * 65536;

  // issue phase-1 tile 0 staging early
  stage16k(HswB, lds + 32768, tid);

  // stage A rows (n0..n0+63) bf16-swizzled into [0,32K)
#pragma unroll
  for (int j = 0; j < 8; ++j) {
    int c = tid + j * 256;
    int r = c >> 5;
    int d0 = (c & 31) * 8;
    const float4* src = (const float4*)(hb + (n0 + r) * 256 + d0);
    float4 x = src[0], y = src[1];
    short8 v;
    v[0] = (short)f2bf(x.x); v[1] = (short)f2bf(x.y);
    v[2] = (short)f2bf(x.z); v[3] = (short)f2bf(x.w);
    v[4] = (short)f2bf(y.x); v[5] = (short)f2bf(y.y);
    v[6] = (short)f2bf(y.z); v[7] = (short)f2bf(y.w);
    *(short8*)(ldsU + r * 256 + (d0 ^ ((r & 7) << 3))) = v;
  }
  // a [4][256] fp32 -> lds+49152 (aliases B buf1; dead after A_k extraction)
  ((float4*)(lds + 49152))[tid] = ((const float4*)a)[tid];
  __syncthreads();

  // A_k = bf16(h * a_k) in registers: wave's row = w*16+l16, 8 K-steps, 4 k's
  short8 Ak[4][8];
  {
    const int arow = w * 16 + l16;
    const float* al = (const float*)(lds + 49152);
#pragma unroll
    for (int ks = 0; ks < 8; ++ks) {
      int d0 = ks * 32 + lhi * 8;
      short8 hv = *(const short8*)(ldsU + arow * 256 + (d0 ^ ((arow & 7) << 3)));
      float hf[8];
#pragma unroll
      for (int jj = 0; jj < 8; ++jj) hf[jj] = bf2f(hv[jj]);
#pragma unroll
      for (int k = 0; k < 4; ++k) {
        const float4* a4 = (const float4*)(al + k * 256 + d0);
        float4 p = a4[0], qv = a4[1];
        short8 o;
        o[0] = (short)f2bf(hf[0] * p.x);  o[1] = (short)f2bf(hf[1] * p.y);
        o[2] = (short)f2bf(hf[2] * p.z);  o[3] = (short)f2bf(hf[3] * p.w);
        o[4] = (short)f2bf(hf[4] * qv.x); o[5] = (short)f2bf(hf[5] * qv.y);
        o[6] = (short)f2bf(hf[6] * qv.z); o[7] = (short)f2bf(hf[7] * qv.w);
        Ak[k][ks] = o;
      }
    }
  }
  __syncthreads();  // a_lds region must be dead before tile-1 staging

  // ---- Phase 1: scores + merge ----
  floatx4 logits[16];
  const int* adjbase = adjb + (n0 + w * 16 + lhi * 4) * 256 + l16;
#pragma unroll
  for (int t8 = 0; t8 < 8; ++t8) {
    const int cur = t8 & 1;
    if (t8 < 7)
      stage16k(HswB + (t8 + 1) * 32 * 256, lds + 32768 + (1 - cur) * 16384, tid);
    int adjv[2][4];
#pragma unroll
    for (int mf = 0; mf < 2; ++mf)
#pragma unroll
      for (int r = 0; r < 4; ++r)
        adjv[mf][r] = adjbase[r * 256 + t8 * 32 + mf * 16];
    floatx4 acc[2][4];
#pragma unroll
    for (int mf = 0; mf < 2; ++mf)
#pragma unroll
      for (int k = 0; k < 4; ++k) {
        floatx4 z = {0.f, 0.f, 0.f, 0.f};
        acc[mf][k] = z;
      }
    const unsigned short* Bt = (const unsigned short*)(lds + 32768 + cur * 16384);
#pragma unroll
    for (int ks = 0; ks < 8; ++ks) {
      int d0 = ks * 32 + lhi * 8;
      short8 b0 = *(const short8*)(Bt + l16 * 256 + (d0 ^ ((l16 & 7) << 3)));
      short8 b1 = *(const short8*)(Bt + (16 + l16) * 256 + (d0 ^ ((l16 & 7) << 3)));
#pragma unroll
      for (int k = 0; k < 4; ++k) {
        acc[0][k] = __builtin_amdgcn_mfma_f32_16x16x32_bf16(Ak[k][ks], b0, acc[0][k], 0, 0, 0);
        acc[1][k] = __builtin_amdgcn_mfma_f32_16x16x32_bf16(Ak[k][ks], b1, acc[1][k], 0, 0, 0);
      }
    }
#pragma unroll
    for (int mf = 0; mf < 2; ++mf) {
      floatx4 L;
#pragma unroll
      for (int r = 0; r < 4; ++r) {
        int av = adjv[mf][r];
        float s = NEGM;
        s = (av == 1) ? acc[mf][0][r] : s;
        s = (av == 2) ? acc[mf][1][r] : s;
        s = (av == 3) ? acc[mf][2][r] : s;
        s = (av == 4) ? acc[mf][3][r] : s;
        s = (s > 0.f) ? s : LEAKY * s;  // leaky(NEG) still -> exp 0
        L[r] = s;
      }
      logits[t8 * 2 + mf] = L;
    }
    __syncthreads();
  }

  // issue phase-2 tile 0 staging, overlap with softmax
  stage16k(HTswB, lds + 32768, tid);

  // ---- in-register softmax (row = lhi*4+r, m over {frag, l16}) ----
  float mx[4], sum[4], inv[4];
#pragma unroll
  for (int r = 0; r < 4; ++r) {
    float m = logits[0][r];
#pragma unroll
    for (int f = 1; f < 16; ++f) m = fmaxf(m, logits[f][r]);
#pragma unroll
    for (int s = 1; s < 16; s <<= 1) m = fmaxf(m, __shfl_xor(m, s));
    mx[r] = m;
    sum[r] = 0.f;
  }
#pragma unroll
  for (int f = 0; f < 16; ++f)
#pragma unroll
    for (int r = 0; r < 4; ++r) {
      float e = __expf(logits[f][r] - mx[r]);
      logits[f][r] = e;
      sum[r] += e;
    }
#pragma unroll
  for (int r = 0; r < 4; ++r) {
#pragma unroll
    for (int s = 1; s < 16; s <<= 1) sum[r] += __shfl_xor(sum[r], s);
    inv[r] = 1.f / sum[r];
  }
  // alpha bf16, swizzled, into [0,32K) (Asw is dead)
#pragma unroll
  for (int f = 0; f < 16; ++f)
#pragma unroll
    for (int r = 0; r < 4; ++r) {
      int row = w * 16 + lhi * 4 + r;
      int mcol = f * 16 + l16;
      ldsU[row * 256 + (mcol ^ ((row & 7) << 3))] = f2bf(logits[f][r] * inv[r]);
    }
  __syncthreads();

  // ---- Phase 2: out = alpha @ H  (B from HTsw: K=m contiguous) ----
  short8 af[8];
  {
    const int arow = w * 16 + l16;
#pragma unroll
    for (int ks = 0; ks < 8; ++ks) {
      int m0 = ks * 32 + lhi * 8;
      af[ks] = *(const short8*)(ldsU + arow * 256 + (m0 ^ ((arow & 7) << 3)));
    }
  }
  floatx4 oa[8][2];
#pragma unroll
  for (int dt = 0; dt < 8; ++dt) {
    floatx4 z = {0.f, 0.f, 0.f, 0.f};
    oa[dt][0] = z; oa[dt][1] = z;
  }
#pragma unroll
  for (int dt = 0; dt < 8; ++dt) {
    const int cur = dt & 1;
    if (dt < 7)
      stage16k(HTswB + (dt + 1) * 32 * 256, lds + 32768 + (1 - cur) * 16384, tid);
    const unsigned short* Bt = (const unsigned short*)(lds + 32768 + cur * 16384);
#pragma unroll
    for (int ks = 0; ks < 8; ++ks) {
      int m0 = ks * 32 + lhi * 8;
      short8 b0 = *(const short8*)(Bt + l16 * 256 + (m0 ^ ((l16 & 7) << 3)));
      short8 b1 = *(const short8*)(Bt + (16 + l16) * 256 + (m0 ^ ((l16 & 7) << 3)));
      oa[dt][0] = __builtin_amdgcn_mfma_f32_16x16x32_bf16(af[ks], b0, oa[dt][0], 0, 0, 0);
      oa[dt][1] = __builtin_amdgcn_mfma_f32_16x16x32_bf16(af[ks], b1, oa[dt][1], 0, 0, 0);
    }
    __syncthreads();
  }

  // ---- epilogue: L2 normalize + residual ----
  float ssq[4] = {0.f, 0.f, 0.f, 0.f};
#pragma unroll
  for (int dt = 0; dt < 8; ++dt)
#pragma unroll
    for (int df = 0; df < 2; ++df)
#pragma unroll
      for (int r = 0; r < 4; ++r) ssq[r] += oa[dt][df][r] * oa[dt][df][r];
#pragma unroll
  for (int r = 0; r < 4; ++r) {
#pragma unroll
    for (int s = 1; s < 16; s <<= 1) ssq[r] += __shfl_xor(ssq[r], s);
  }
  float innv[4];
#pragma unroll
  for (int r = 0; r < 4; ++r) innv[r] = 1.f / fmaxf(sqrtf(ssq[r]), 1e-12f);
  float* ob = out + b * 65536;
#pragma unroll
  for (int dt = 0; dt < 8; ++dt)
#pragma unroll
    for (int df = 0; df < 2; ++df)
#pragma unroll
      for (int r = 0; r < 4; ++r) {
        int n = n0 + w * 16 + lhi * 4 + r;
        int d = dt * 32 + df * 16 + l16;
        ob[n * 256 + d] = oa[dt][df][r] * innv[r] + hb[n * 256 + d];
      }
}

extern "C" void kernel_launch(void* const* d_in, const int* in_sizes, int n_in,
                              void* d_out, int out_size, void* d_ws, size_t ws_size,
                              hipStream_t stream) {
  const float* h = (const float*)d_in[0];
  const int* adj = (const int*)d_in[1];
  const float* a = (const float*)d_in[2];
  float* out = (float*)d_out;
  unsigned short* Hsw = (unsigned short*)d_ws;
  unsigned short* HTsw = Hsw + 64 * 256 * 256;
  prep_kernel<<<256, 256, 0, stream>>>(h, Hsw, HTsw);
  fused_kernel<<<256, 256, 0, stream>>>(h, adj, a, out, Hsw, HTsw);
}